// Round 1
// baseline (147.588 us; speedup 1.0000x reference)
//
#include <hip/hip_runtime.h>

#define N_HEAD 4
#define F_IN   32
#define F_OUT  32
#define DEG    16

// Kernel 1: hp[n][h][o] = sum_f h[n,f] * w[h,f,o]; also a_src/a_dst per (n,h).
// 256 threads handle 2 nodes (128 threads/node: h = t2>>5, o = t2&31).
__global__ __launch_bounds__(256) void gat_proj(
    const float* __restrict__ h, const float* __restrict__ w,
    const float* __restrict__ fc_w,
    float* __restrict__ hp, float* __restrict__ asrc, float* __restrict__ adst,
    int N)
{
    __shared__ float wlds[N_HEAD * F_IN * F_OUT];   // 16 KB
    __shared__ float hrow[2 * F_IN];
    int t = threadIdx.x;
    #pragma unroll
    for (int i = t; i < N_HEAD * F_IN * F_OUT; i += 256) wlds[i] = w[i];
    int node0 = blockIdx.x * 2;
    if (t < 2 * F_IN) {
        int idx = node0 * F_IN + t;
        hrow[t] = (idx < N * F_IN) ? h[idx] : 0.f;
    }
    __syncthreads();

    int local = t >> 7;            // which of the 2 nodes
    int node  = node0 + local;
    if (node >= N) return;
    int t2 = t & 127;
    int hh = t2 >> 5;              // head
    int o  = t2 & 31;              // out feature

    const float* hr = &hrow[local * F_IN];
    const float* wp = &wlds[hh * F_IN * F_OUT + o];
    float val = 0.f;
    #pragma unroll
    for (int f = 0; f < F_IN; ++f) val = fmaf(hr[f], wp[f * F_OUT], val);

    hp[(size_t)node * (N_HEAD * F_OUT) + hh * F_OUT + o] = val;

    // reduce val*w_src / val*w_dst over o (32 aligned lanes within the wave)
    float ps = val * fc_w[o];
    float pd = val * fc_w[F_OUT + o];
    #pragma unroll
    for (int m = 16; m >= 1; m >>= 1) {
        ps += __shfl_xor(ps, m, 64);
        pd += __shfl_xor(pd, m, 64);
    }
    if (o == 0) {
        asrc[node * N_HEAD + hh] = ps;
        adst[node * N_HEAD + hh] = pd;
    }
}

// Kernel 2: one wave per node. half = lane>>5 picks heads {2*half, 2*half+1};
// o = lane&31 is the output feature. Softmax over the node's 16 edges via shfl.
__global__ __launch_bounds__(256) void gat_agg(
    const int* __restrict__ dst, const float* __restrict__ hp,
    const float* __restrict__ asrc, const float* __restrict__ adst,
    const float* __restrict__ fc_b, const float* __restrict__ bias,
    float* __restrict__ out, int N)
{
    int wave = (int)((blockIdx.x * 256 + threadIdx.x) >> 6);
    int lane = threadIdx.x & 63;
    if (wave >= N) return;                 // whole wave exits together
    int node = wave;
    int o    = lane & 31;
    int half = lane >> 5;                  // 0: heads 0,1  1: heads 2,3
    int h0   = half * 2;

    float b = fc_b[0];

    // lanes 0..15 hold the 16 dst indices
    int dval = 0;
    if (lane < DEG) dval = dst[node * DEG + lane];

    // my edge k (duplicated across the two 16-lane subgroups of each half)
    int k_id = lane & 15;
    int dk_self = __shfl(dval, k_id, 64);

    float as0 = asrc[node * N_HEAD + h0];
    float as1 = asrc[node * N_HEAD + h0 + 1];
    const float2* adst2 = (const float2*)adst;   // [n][4] -> float2 per half
    float2 ad = adst2[(size_t)dk_self * 2 + half];

    float e0 = as0 + ad.x + b;
    float e1 = as1 + ad.y + b;
    e0 = e0 > 0.f ? e0 : 0.2f * e0;
    e1 = e1 > 0.f ? e1 : 0.2f * e1;

    // max over the 16 edges (16-lane aligned subgroups)
    float m0 = e0, m1 = e1;
    #pragma unroll
    for (int m = 8; m >= 1; m >>= 1) {
        m0 = fmaxf(m0, __shfl_xor(m0, m, 64));
        m1 = fmaxf(m1, __shfl_xor(m1, m, 64));
    }
    float p0 = __expf(e0 - m0), p1 = __expf(e1 - m1);
    float s0 = p0, s1 = p1;
    #pragma unroll
    for (int m = 8; m >= 1; m >>= 1) {
        s0 += __shfl_xor(s0, m, 64);
        s1 += __shfl_xor(s1, m, 64);
    }
    float att0 = p0 / s0, att1 = p1 / s1;

    // aggregate: acc[o] = sum_k att_k * hp[dst_k][h][o]
    float acc0 = 0.f, acc1 = 0.f;
    #pragma unroll
    for (int k = 0; k < DEG; ++k) {
        int dk   = __shfl(dval, k, 64);
        float a0 = __shfl(att0, half * 32 + k, 64);
        float a1 = __shfl(att1, half * 32 + k, 64);
        const float* row = &hp[(size_t)dk * (N_HEAD * F_OUT) + half * 64 + o];
        acc0 = fmaf(a0, row[0],  acc0);
        acc1 = fmaf(a1, row[32], acc1);
    }

    // mean over 4 heads: half0 partial + half1 partial, then /4 + bias
    float part  = acc0 + acc1;
    float other = __shfl(part, o + 32, 64);   // lane o+32 holds heads {2,3}
    if (half == 0) {
        out[(size_t)node * F_OUT + o] = 0.25f * (part + other) + bias[o];
    }
}

extern "C" void kernel_launch(void* const* d_in, const int* in_sizes, int n_in,
                              void* d_out, int out_size, void* d_ws, size_t ws_size,
                              hipStream_t stream) {
    const float* h      = (const float*)d_in[0];
    const int*   eidx   = (const int*)  d_in[1];
    const float* w      = (const float*)d_in[2];
    const float* fc_w   = (const float*)d_in[3];
    const float* fc_b   = (const float*)d_in[4];
    const float* bias   = (const float*)d_in[5];

    int N = in_sizes[0] / F_IN;
    int E = in_sizes[1] / 2;
    const int* dst = eidx + E;     // edge_index[1]

    float* hp   = (float*)d_ws;                                // N*128 floats
    float* asrc = hp + (size_t)N * N_HEAD * F_OUT;             // N*4
    float* adst = asrc + (size_t)N * N_HEAD;                   // N*4
    float* out  = (float*)d_out;

    gat_proj<<<(N + 1) / 2, 256, 0, stream>>>(h, w, fc_w, hp, asrc, adst, N);
    gat_agg <<<(N + 3) / 4, 256, 0, stream>>>(dst, hp, asrc, adst, fc_b, bias, out, N);
}

// Round 2
// 111.086 us; speedup vs baseline: 1.3286x; 1.3286x over previous
//
#include <hip/hip_runtime.h>

#define N_HEAD 4
#define F_IN   32
#define F_OUT  32
#define DEG    16

__device__ __forceinline__ float4 fma4(float a, float4 x, float4 acc) {
    acc.x = fmaf(a, x.x, acc.x);
    acc.y = fmaf(a, x.y, acc.y);
    acc.z = fmaf(a, x.z, acc.z);
    acc.w = fmaf(a, x.w, acc.w);
    return acc;
}

__device__ __forceinline__ float4 shflxor4(float4 v, int m) {
    float4 r;
    r.x = __shfl_xor(v.x, m, 64);
    r.y = __shfl_xor(v.y, m, 64);
    r.z = __shfl_xor(v.z, m, 64);
    r.w = __shfl_xor(v.w, m, 64);
    return r;
}

// Kernel 1: hp[n][h][o] = sum_f h[n,f]*w[h,f,o], plus a_src/a_dst per (n,h).
// Block = 256 threads = 4 waves; each wave handles 8 nodes.
// Lane: p = lane>>5 (node subgroup), hh = (lane&31)>>3, q = lane&7 (o-quad).
// Each lane computes 4 nodes x float4 of outputs. w staged in LDS (b128
// reads, 4 f per read); h read from global (wave-uniform addr -> 1-line
// broadcast, VMEM pipe instead of LDS pipe).
__global__ __launch_bounds__(256) void gat_proj(
    const float* __restrict__ h, const float* __restrict__ w,
    const float* __restrict__ fc_w,
    float* __restrict__ hp, float* __restrict__ asrc, float* __restrict__ adst,
    int N)
{
    __shared__ float4 wlds[N_HEAD * F_IN * F_OUT / 4];   // 1024 float4 = 16 KB
    int t = threadIdx.x;
    const float4* w4g = (const float4*)w;
    wlds[t]       = w4g[t];
    wlds[t + 256] = w4g[t + 256];
    wlds[t + 512] = w4g[t + 512];
    wlds[t + 768] = w4g[t + 768];
    __syncthreads();

    int wid  = t >> 6;
    int lane = t & 63;
    int p    = lane >> 5;
    int sub  = lane & 31;
    int hh   = sub >> 3;
    int q    = sub & 7;
    int node0 = blockIdx.x * 32;
    int base  = node0 + wid * 8 + p * 4;   // first of this lane-group's 4 nodes

    float4 acc[4];
    #pragma unroll
    for (int m = 0; m < 4; ++m) acc[m] = make_float4(0.f, 0.f, 0.f, 0.f);

    const float4* h4 = (const float4*)h;
    #pragma unroll
    for (int c = 0; c < 8; ++c) {        // f-chunk of 4
        float4 wv0 = wlds[hh * 256 + (4 * c + 0) * 8 + q];
        float4 wv1 = wlds[hh * 256 + (4 * c + 1) * 8 + q];
        float4 wv2 = wlds[hh * 256 + (4 * c + 2) * 8 + q];
        float4 wv3 = wlds[hh * 256 + (4 * c + 3) * 8 + q];
        #pragma unroll
        for (int m = 0; m < 4; ++m) {
            int node = base + m;
            int nc   = node < N ? node : N - 1;
            float4 hv = h4[(size_t)nc * 8 + c];   // h[node][4c..4c+3]
            acc[m] = fma4(hv.x, wv0, acc[m]);
            acc[m] = fma4(hv.y, wv1, acc[m]);
            acc[m] = fma4(hv.z, wv2, acc[m]);
            acc[m] = fma4(hv.w, wv3, acc[m]);
        }
    }

    // a_src/a_dst partial dots, reduce over q (lanes stride 1 within 8)
    float4 fs4 = ((const float4*)fc_w)[q];
    float4 fd4 = ((const float4*)fc_w)[8 + q];
    float ps[4], pd[4];
    #pragma unroll
    for (int m = 0; m < 4; ++m) {
        ps[m] = acc[m].x * fs4.x + acc[m].y * fs4.y + acc[m].z * fs4.z + acc[m].w * fs4.w;
        pd[m] = acc[m].x * fd4.x + acc[m].y * fd4.y + acc[m].z * fd4.z + acc[m].w * fd4.w;
    }
    #pragma unroll
    for (int msk = 1; msk <= 4; msk <<= 1) {
        #pragma unroll
        for (int m = 0; m < 4; ++m) {
            ps[m] += __shfl_xor(ps[m], msk, 64);
            pd[m] += __shfl_xor(pd[m], msk, 64);
        }
    }

    float4* hp4 = (float4*)hp;
    #pragma unroll
    for (int m = 0; m < 4; ++m) {
        int node = base + m;
        if (node < N) {
            hp4[(size_t)node * 32 + hh * 8 + q] = acc[m];
            if (q == 0) {
                asrc[node * N_HEAD + hh] = ps[m];
                adst[node * N_HEAD + hh] = pd[m];
            }
        }
    }
}

// Kernel 2: one wave per node. In-register softmax (each lane redundantly
// computes all 16 logits for its head), float4 gathers of hp.
// Lane: e2 = lane>>5 (edge parity), hh = (lane&31)>>3, q = lane&7.
__global__ __launch_bounds__(256) void gat_agg(
    const int* __restrict__ dst, const float* __restrict__ hp,
    const float* __restrict__ asrc, const float* __restrict__ adst,
    const float* __restrict__ fc_b, const float* __restrict__ bias,
    float* __restrict__ out, int N)
{
    int wave = (int)((blockIdx.x * 256 + threadIdx.x) >> 6);
    int lane = threadIdx.x & 63;
    if (wave >= N) return;
    int node = wave;
    int e2 = lane >> 5;
    int sub = lane & 31;
    int hh = sub >> 3;
    int q  = sub & 7;

    // all 16 dst indices in registers (wave-uniform int4 loads)
    const int4* dr4 = (const int4*)(dst + (size_t)node * DEG);
    int4 d0 = dr4[0], d1 = dr4[1], d2 = dr4[2], d3 = dr4[3];
    int dk[16] = { d0.x, d0.y, d0.z, d0.w, d1.x, d1.y, d1.z, d1.w,
                   d2.x, d2.y, d2.z, d2.w, d3.x, d3.y, d3.z, d3.w };

    float as = asrc[node * N_HEAD + hh];
    float b  = fc_b[0];

    float e[16];
    #pragma unroll
    for (int k = 0; k < 16; ++k) {
        float ad = adst[dk[k] * N_HEAD + hh];   // 1-2 lines per instr
        float v  = as + ad + b;
        e[k] = v > 0.f ? v : 0.2f * v;
    }
    float mx = e[0];
    #pragma unroll
    for (int k = 1; k < 16; ++k) mx = fmaxf(mx, e[k]);
    float s = 0.f;
    #pragma unroll
    for (int k = 0; k < 16; ++k) { e[k] = __expf(e[k] - mx); s += e[k]; }
    float inv = 1.0f / s;

    // aggregate: 8 iterations, 2 edges at a time (parity split across halves)
    float4 acc = make_float4(0.f, 0.f, 0.f, 0.f);
    const float4* hp4 = (const float4*)hp;
    #pragma unroll
    for (int i = 0; i < 8; ++i) {
        int   dki = e2 ? dk[2 * i + 1] : dk[2 * i];
        float att = (e2 ? e[2 * i + 1] : e[2 * i]) * inv;
        float4 v = hp4[(size_t)dki * 32 + hh * 8 + q];
        acc = fma4(att, v, acc);
    }

    // sum over parity (xor 32) then over heads (xor 8, 16); /4 + bias
    float4 r;
    r = shflxor4(acc, 32); acc.x += r.x; acc.y += r.y; acc.z += r.z; acc.w += r.w;
    r = shflxor4(acc, 8);  acc.x += r.x; acc.y += r.y; acc.z += r.z; acc.w += r.w;
    r = shflxor4(acc, 16); acc.x += r.x; acc.y += r.y; acc.z += r.z; acc.w += r.w;

    if (lane < 8) {   // e2=0, hh=0, q=lane
        float4 b4 = ((const float4*)bias)[q];
        float4 o4;
        o4.x = 0.25f * acc.x + b4.x;
        o4.y = 0.25f * acc.y + b4.y;
        o4.z = 0.25f * acc.z + b4.z;
        o4.w = 0.25f * acc.w + b4.w;
        ((float4*)out)[(size_t)node * 8 + q] = o4;
    }
}

extern "C" void kernel_launch(void* const* d_in, const int* in_sizes, int n_in,
                              void* d_out, int out_size, void* d_ws, size_t ws_size,
                              hipStream_t stream) {
    const float* h    = (const float*)d_in[0];
    const int*   eidx = (const int*)  d_in[1];
    const float* w    = (const float*)d_in[2];
    const float* fc_w = (const float*)d_in[3];
    const float* fc_b = (const float*)d_in[4];
    const float* bias = (const float*)d_in[5];

    int N = in_sizes[0] / F_IN;
    int E = in_sizes[1] / 2;
    const int* dst = eidx + E;     // edge_index[1]

    float* hp   = (float*)d_ws;                               // N*128 floats
    float* asrc = hp + (size_t)N * N_HEAD * F_OUT;            // N*4
    float* adst = asrc + (size_t)N * N_HEAD;                  // N*4
    float* out  = (float*)d_out;

    gat_proj<<<(N + 31) / 32, 256, 0, stream>>>(h, w, fc_w, hp, asrc, adst, N);
    gat_agg <<<(N + 3) / 4,   256, 0, stream>>>(dst, hp, asrc, adst, fc_b, bias, out, N);
}

// Round 3
// 108.388 us; speedup vs baseline: 1.3617x; 1.0249x over previous
//
#include <hip/hip_runtime.h>
#include <hip/hip_fp16.h>

#define N_HEAD 4
#define F_IN   32
#define F_OUT  32
#define DEG    16

union H4 { ushort4 u; __half h[4]; };

__device__ __forceinline__ float4 fma4(float a, float4 x, float4 acc) {
    acc.x = fmaf(a, x.x, acc.x);
    acc.y = fmaf(a, x.y, acc.y);
    acc.z = fmaf(a, x.z, acc.z);
    acc.w = fmaf(a, x.w, acc.w);
    return acc;
}

__device__ __forceinline__ float4 shflxor4(float4 v, int m) {
    float4 r;
    r.x = __shfl_xor(v.x, m, 64);
    r.y = __shfl_xor(v.y, m, 64);
    r.z = __shfl_xor(v.z, m, 64);
    r.w = __shfl_xor(v.w, m, 64);
    return r;
}

// Kernel 1: hp[n][h][o] = sum_f h[n,f]*w[h,f,o] (stored fp16),
// plus a_src/a_dst per (n,h) in fp32.
// Block = 256 threads = 4 waves; each wave handles 8 nodes.
// Lane: p = lane>>5, hh = (lane&31)>>3, q = lane&7. 4 nodes x float4 per lane.
__global__ __launch_bounds__(256) void gat_proj(
    const float* __restrict__ h, const float* __restrict__ w,
    const float* __restrict__ fc_w,
    ushort4* __restrict__ hp, float* __restrict__ asrc, float* __restrict__ adst,
    int N)
{
    __shared__ float4 wlds[N_HEAD * F_IN * F_OUT / 4];   // 16 KB
    int t = threadIdx.x;
    const float4* w4g = (const float4*)w;
    wlds[t]       = w4g[t];
    wlds[t + 256] = w4g[t + 256];
    wlds[t + 512] = w4g[t + 512];
    wlds[t + 768] = w4g[t + 768];
    __syncthreads();

    int wid  = t >> 6;
    int lane = t & 63;
    int p    = lane >> 5;
    int sub  = lane & 31;
    int hh   = sub >> 3;
    int q    = sub & 7;
    int node0 = blockIdx.x * 32;
    int base  = node0 + wid * 8 + p * 4;
    bool full = (node0 + 32 <= N);

    float4 acc[4];
    #pragma unroll
    for (int m = 0; m < 4; ++m) acc[m] = make_float4(0.f, 0.f, 0.f, 0.f);

    const float4* h4 = (const float4*)h;
    if (full) {
        #pragma unroll
        for (int c = 0; c < 8; ++c) {
            float4 wv0 = wlds[hh * 256 + (4 * c + 0) * 8 + q];
            float4 wv1 = wlds[hh * 256 + (4 * c + 1) * 8 + q];
            float4 wv2 = wlds[hh * 256 + (4 * c + 2) * 8 + q];
            float4 wv3 = wlds[hh * 256 + (4 * c + 3) * 8 + q];
            #pragma unroll
            for (int m = 0; m < 4; ++m) {
                float4 hv = h4[(size_t)(base + m) * 8 + c];
                acc[m] = fma4(hv.x, wv0, acc[m]);
                acc[m] = fma4(hv.y, wv1, acc[m]);
                acc[m] = fma4(hv.z, wv2, acc[m]);
                acc[m] = fma4(hv.w, wv3, acc[m]);
            }
        }
    } else {
        #pragma unroll
        for (int c = 0; c < 8; ++c) {
            float4 wv0 = wlds[hh * 256 + (4 * c + 0) * 8 + q];
            float4 wv1 = wlds[hh * 256 + (4 * c + 1) * 8 + q];
            float4 wv2 = wlds[hh * 256 + (4 * c + 2) * 8 + q];
            float4 wv3 = wlds[hh * 256 + (4 * c + 3) * 8 + q];
            #pragma unroll
            for (int m = 0; m < 4; ++m) {
                int node = base + m;
                int nc   = node < N ? node : N - 1;
                float4 hv = h4[(size_t)nc * 8 + c];
                acc[m] = fma4(hv.x, wv0, acc[m]);
                acc[m] = fma4(hv.y, wv1, acc[m]);
                acc[m] = fma4(hv.z, wv2, acc[m]);
                acc[m] = fma4(hv.w, wv3, acc[m]);
            }
        }
    }

    // a_src/a_dst partial dots, reduce over q (xor 1,2,4)
    float4 fs4 = ((const float4*)fc_w)[q];
    float4 fd4 = ((const float4*)fc_w)[8 + q];
    float ps[4], pd[4];
    #pragma unroll
    for (int m = 0; m < 4; ++m) {
        ps[m] = acc[m].x * fs4.x + acc[m].y * fs4.y + acc[m].z * fs4.z + acc[m].w * fs4.w;
        pd[m] = acc[m].x * fd4.x + acc[m].y * fd4.y + acc[m].z * fd4.z + acc[m].w * fd4.w;
    }
    #pragma unroll
    for (int msk = 1; msk <= 4; msk <<= 1) {
        #pragma unroll
        for (int m = 0; m < 4; ++m) {
            ps[m] += __shfl_xor(ps[m], msk, 64);
            pd[m] += __shfl_xor(pd[m], msk, 64);
        }
    }

    #pragma unroll
    for (int m = 0; m < 4; ++m) {
        int node = base + m;
        if (full || node < N) {
            H4 pk;
            pk.h[0] = __float2half_rn(acc[m].x);
            pk.h[1] = __float2half_rn(acc[m].y);
            pk.h[2] = __float2half_rn(acc[m].z);
            pk.h[3] = __float2half_rn(acc[m].w);
            hp[(size_t)node * 32 + hh * 8 + q] = pk.u;
            if (q == 0) {
                asrc[node * N_HEAD + hh] = ps[m];
                adst[node * N_HEAD + hh] = pd[m];
            }
        }
    }
}

// Kernel 2: one wave per node. In-register softmax (unnormalized p,
// scale once at the end), fp16 hp gathers (ushort4 = 4 outs per lane;
// each half-wave instruction covers one full 256 B row).
__global__ __launch_bounds__(256) void gat_agg(
    const int* __restrict__ dst, const ushort4* __restrict__ hp,
    const float* __restrict__ asrc, const float* __restrict__ adst,
    const float* __restrict__ fc_b, const float* __restrict__ bias,
    float* __restrict__ out, int N)
{
    int wave = (int)((blockIdx.x * 256 + threadIdx.x) >> 6);
    int lane = threadIdx.x & 63;
    if (wave >= N) return;
    int node = wave;
    int e2 = lane >> 5;
    int sub = lane & 31;
    int hh = sub >> 3;
    int q  = sub & 7;

    const int4* dr4 = (const int4*)(dst + (size_t)node * DEG);
    int4 d0 = dr4[0], d1 = dr4[1], d2 = dr4[2], d3 = dr4[3];
    int dk[16] = { d0.x, d0.y, d0.z, d0.w, d1.x, d1.y, d1.z, d1.w,
                   d2.x, d2.y, d2.z, d2.w, d3.x, d3.y, d3.z, d3.w };

    float as = asrc[node * N_HEAD + hh];
    float b  = fc_b[0];

    float e[16];
    #pragma unroll
    for (int k = 0; k < 16; ++k) {
        float ad = adst[dk[k] * N_HEAD + hh];
        float v  = as + ad + b;
        e[k] = v > 0.f ? v : 0.2f * v;
    }
    float mx = e[0];
    #pragma unroll
    for (int k = 1; k < 16; ++k) mx = fmaxf(mx, e[k]);
    float s = 0.f;
    #pragma unroll
    for (int k = 0; k < 16; ++k) { e[k] = __expf(e[k] - mx); s += e[k]; }
    float inv = 1.0f / s;

    // aggregate (unnormalized): 8 iterations, 2 edges split across halves
    float4 acc = make_float4(0.f, 0.f, 0.f, 0.f);
    #pragma unroll
    for (int i = 0; i < 8; ++i) {
        int   dki = e2 ? dk[2 * i + 1] : dk[2 * i];
        float p   = e2 ? e[2 * i + 1] : e[2 * i];
        H4 pk;
        pk.u = hp[(size_t)dki * 32 + hh * 8 + q];
        float4 v = make_float4(__half2float(pk.h[0]), __half2float(pk.h[1]),
                               __half2float(pk.h[2]), __half2float(pk.h[3]));
        acc = fma4(p, v, acc);
    }
    acc.x *= inv; acc.y *= inv; acc.z *= inv; acc.w *= inv;

    // sum over parity (xor 32) then heads (xor 8, 16); /4 + bias
    float4 r;
    r = shflxor4(acc, 32); acc.x += r.x; acc.y += r.y; acc.z += r.z; acc.w += r.w;
    r = shflxor4(acc, 8);  acc.x += r.x; acc.y += r.y; acc.z += r.z; acc.w += r.w;
    r = shflxor4(acc, 16); acc.x += r.x; acc.y += r.y; acc.z += r.z; acc.w += r.w;

    if (lane < 8) {   // e2=0, hh=0, q=lane
        float4 b4 = ((const float4*)bias)[q];
        float4 o4;
        o4.x = 0.25f * acc.x + b4.x;
        o4.y = 0.25f * acc.y + b4.y;
        o4.z = 0.25f * acc.z + b4.z;
        o4.w = 0.25f * acc.w + b4.w;
        ((float4*)out)[(size_t)node * 8 + q] = o4;
    }
}

extern "C" void kernel_launch(void* const* d_in, const int* in_sizes, int n_in,
                              void* d_out, int out_size, void* d_ws, size_t ws_size,
                              hipStream_t stream) {
    const float* h    = (const float*)d_in[0];
    const int*   eidx = (const int*)  d_in[1];
    const float* w    = (const float*)d_in[2];
    const float* fc_w = (const float*)d_in[3];
    const float* fc_b = (const float*)d_in[4];
    const float* bias = (const float*)d_in[5];

    int N = in_sizes[0] / F_IN;
    int E = in_sizes[1] / 2;
    const int* dst = eidx + E;     // edge_index[1]

    ushort4* hp  = (ushort4*)d_ws;                             // N*32 ushort4 (fp16)
    float* asrc  = (float*)(hp + (size_t)N * 32);              // N*4
    float* adst  = asrc + (size_t)N * N_HEAD;                  // N*4
    float* out   = (float*)d_out;

    gat_proj<<<(N + 31) / 32, 256, 0, stream>>>(h, w, fc_w, hp, asrc, adst, N);
    gat_agg <<<(N + 3) / 4,   256, 0, stream>>>(dst, hp, asrc, adst, fc_b, bias, out, N);
}

// Round 4
// 102.386 us; speedup vs baseline: 1.4415x; 1.0586x over previous
//
#include <hip/hip_runtime.h>
#include <hip/hip_fp16.h>

#define N_HEAD 4
#define F_IN   32
#define F_OUT  32
#define DEG    16

union H4 { ushort4 u; __half h[4]; };
union H8 { uint4 u; __half h[8]; };

__device__ __forceinline__ float4 fma4(float a, float4 x, float4 acc) {
    acc.x = fmaf(a, x.x, acc.x);
    acc.y = fmaf(a, x.y, acc.y);
    acc.z = fmaf(a, x.z, acc.z);
    acc.w = fmaf(a, x.w, acc.w);
    return acc;
}

// Kernel 1 (unchanged from R3): hp[n][h][o] fp16, a_src/a_dst fp32.
__global__ __launch_bounds__(256) void gat_proj(
    const float* __restrict__ h, const float* __restrict__ w,
    const float* __restrict__ fc_w,
    ushort4* __restrict__ hp, float* __restrict__ asrc, float* __restrict__ adst,
    int N)
{
    __shared__ float4 wlds[N_HEAD * F_IN * F_OUT / 4];   // 16 KB
    int t = threadIdx.x;
    const float4* w4g = (const float4*)w;
    wlds[t]       = w4g[t];
    wlds[t + 256] = w4g[t + 256];
    wlds[t + 512] = w4g[t + 512];
    wlds[t + 768] = w4g[t + 768];
    __syncthreads();

    int wid  = t >> 6;
    int lane = t & 63;
    int p    = lane >> 5;
    int sub  = lane & 31;
    int hh   = sub >> 3;
    int q    = sub & 7;
    int node0 = blockIdx.x * 32;
    int base  = node0 + wid * 8 + p * 4;
    bool full = (node0 + 32 <= N);

    float4 acc[4];
    #pragma unroll
    for (int m = 0; m < 4; ++m) acc[m] = make_float4(0.f, 0.f, 0.f, 0.f);

    const float4* h4 = (const float4*)h;
    if (full) {
        #pragma unroll
        for (int c = 0; c < 8; ++c) {
            float4 wv0 = wlds[hh * 256 + (4 * c + 0) * 8 + q];
            float4 wv1 = wlds[hh * 256 + (4 * c + 1) * 8 + q];
            float4 wv2 = wlds[hh * 256 + (4 * c + 2) * 8 + q];
            float4 wv3 = wlds[hh * 256 + (4 * c + 3) * 8 + q];
            #pragma unroll
            for (int m = 0; m < 4; ++m) {
                float4 hv = h4[(size_t)(base + m) * 8 + c];
                acc[m] = fma4(hv.x, wv0, acc[m]);
                acc[m] = fma4(hv.y, wv1, acc[m]);
                acc[m] = fma4(hv.z, wv2, acc[m]);
                acc[m] = fma4(hv.w, wv3, acc[m]);
            }
        }
    } else {
        #pragma unroll
        for (int c = 0; c < 8; ++c) {
            float4 wv0 = wlds[hh * 256 + (4 * c + 0) * 8 + q];
            float4 wv1 = wlds[hh * 256 + (4 * c + 1) * 8 + q];
            float4 wv2 = wlds[hh * 256 + (4 * c + 2) * 8 + q];
            float4 wv3 = wlds[hh * 256 + (4 * c + 3) * 8 + q];
            #pragma unroll
            for (int m = 0; m < 4; ++m) {
                int node = base + m;
                int nc   = node < N ? node : N - 1;
                float4 hv = h4[(size_t)nc * 8 + c];
                acc[m] = fma4(hv.x, wv0, acc[m]);
                acc[m] = fma4(hv.y, wv1, acc[m]);
                acc[m] = fma4(hv.z, wv2, acc[m]);
                acc[m] = fma4(hv.w, wv3, acc[m]);
            }
        }
    }

    float4 fs4 = ((const float4*)fc_w)[q];
    float4 fd4 = ((const float4*)fc_w)[8 + q];
    float ps[4], pd[4];
    #pragma unroll
    for (int m = 0; m < 4; ++m) {
        ps[m] = acc[m].x * fs4.x + acc[m].y * fs4.y + acc[m].z * fs4.z + acc[m].w * fs4.w;
        pd[m] = acc[m].x * fd4.x + acc[m].y * fd4.y + acc[m].z * fd4.z + acc[m].w * fd4.w;
    }
    #pragma unroll
    for (int msk = 1; msk <= 4; msk <<= 1) {
        #pragma unroll
        for (int m = 0; m < 4; ++m) {
            ps[m] += __shfl_xor(ps[m], msk, 64);
            pd[m] += __shfl_xor(pd[m], msk, 64);
        }
    }

    #pragma unroll
    for (int m = 0; m < 4; ++m) {
        int node = base + m;
        if (full || node < N) {
            H4 pk;
            pk.h[0] = __float2half_rn(acc[m].x);
            pk.h[1] = __float2half_rn(acc[m].y);
            pk.h[2] = __float2half_rn(acc[m].z);
            pk.h[3] = __float2half_rn(acc[m].w);
            hp[(size_t)node * 32 + hh * 8 + q] = pk.u;
            if (q == 0) {
                asrc[node * N_HEAD + hh] = ps[m];
                adst[node * N_HEAD + hh] = pd[m];
            }
        }
    }
}

// Kernel 2 (new): 4 nodes per wave. lane = g*16 + r.
//   g = node sub-index, r = edge index AND output slice index.
//   Slice r of the 256 B hp row = halves [8r, 8r+8) -> head c=r>>2,
//   o-range (r&3)*8.. Each lane: scalar softmax for head c over 16 edges
//   (dst/adst re-reads are L1 broadcasts), then accumulates its slice over
//   all 16 edges with fully-coalesced uint4 gathers (one instr = 4 rows).
//   XCD swizzle: blockIdx%8 selects XCD-contiguous node chunks for L2 reuse.
__global__ __launch_bounds__(256) void gat_agg(
    const int* __restrict__ dst, const uint4* __restrict__ hp,
    const float* __restrict__ asrc, const float* __restrict__ adst,
    const float* __restrict__ fc_b, const float* __restrict__ bias,
    float* __restrict__ out, int N)
{
    int chunk = gridDim.x >> 3;
    int b  = blockIdx.x;
    int vb = (b & 7) * chunk + (b >> 3);
    int t = threadIdx.x;
    int wid = t >> 6, lane = t & 63;
    int g = lane >> 4, r = lane & 15;
    int node  = vb * 16 + wid * 4 + g;
    int nodec = node < N ? node : N - 1;
    int c = r >> 2;                       // head owned by this lane's slice

    // all 16 dst indices of my node (uniform within 16-lane group -> L1 bcast)
    int dk[16];
    #pragma unroll
    for (int k = 0; k < 16; ++k) dk[k] = dst[nodec * DEG + k];

    float as = asrc[nodec * N_HEAD + c];
    float bb = fc_b[0];

    // softmax over the 16 edges for head c (in-register)
    float p[16];
    float mx = -1e30f;
    #pragma unroll
    for (int k = 0; k < 16; ++k) {
        float v = as + adst[dk[k] * N_HEAD + c] + bb;
        v = v > 0.f ? v : 0.2f * v;
        p[k] = v;
        mx = fmaxf(mx, v);
    }
    float s = 0.f;
    #pragma unroll
    for (int k = 0; k < 16; ++k) { p[k] = __expf(p[k] - mx); s += p[k]; }
    float inv = 1.f / s;

    // accumulate slice r over all 16 edges (unnormalized, scale once)
    float acc[8];
    #pragma unroll
    for (int j = 0; j < 8; ++j) acc[j] = 0.f;
    #pragma unroll
    for (int k = 0; k < 16; ++k) {
        H8 v; v.u = hp[(size_t)dk[k] * 16 + r];
        float a = p[k];
        #pragma unroll
        for (int j = 0; j < 8; ++j) acc[j] = fmaf(a, __half2float(v.h[j]), acc[j]);
    }
    #pragma unroll
    for (int j = 0; j < 8; ++j) acc[j] *= inv;

    // head-mean: reduce across lanes differing in bits 2,3 of r (xor 4, 8)
    #pragma unroll
    for (int j = 0; j < 8; ++j) acc[j] += __shfl_xor(acc[j], 4, 64);
    #pragma unroll
    for (int j = 0; j < 8; ++j) acc[j] += __shfl_xor(acc[j], 8, 64);

    if (node < N && r < 4) {              // lanes r<4 hold o in [8r, 8r+8)
        float4 b0 = ((const float4*)bias)[r * 2];
        float4 b1 = ((const float4*)bias)[r * 2 + 1];
        float4 o0, o1;
        o0.x = 0.25f * acc[0] + b0.x;
        o0.y = 0.25f * acc[1] + b0.y;
        o0.z = 0.25f * acc[2] + b0.z;
        o0.w = 0.25f * acc[3] + b0.w;
        o1.x = 0.25f * acc[4] + b1.x;
        o1.y = 0.25f * acc[5] + b1.y;
        o1.z = 0.25f * acc[6] + b1.z;
        o1.w = 0.25f * acc[7] + b1.w;
        ((float4*)out)[(size_t)node * 8 + r * 2]     = o0;
        ((float4*)out)[(size_t)node * 8 + r * 2 + 1] = o1;
    }
}

extern "C" void kernel_launch(void* const* d_in, const int* in_sizes, int n_in,
                              void* d_out, int out_size, void* d_ws, size_t ws_size,
                              hipStream_t stream) {
    const float* h    = (const float*)d_in[0];
    const int*   eidx = (const int*)  d_in[1];
    const float* w    = (const float*)d_in[2];
    const float* fc_w = (const float*)d_in[3];
    const float* fc_b = (const float*)d_in[4];
    const float* bias = (const float*)d_in[5];

    int N = in_sizes[0] / F_IN;
    int E = in_sizes[1] / 2;
    const int* dst = eidx + E;     // edge_index[1]

    ushort4* hp  = (ushort4*)d_ws;                     // N*32 ushort4 (fp16)
    float* asrc  = (float*)(hp + (size_t)N * 32);      // N*4
    float* adst  = asrc + (size_t)N * N_HEAD;          // N*4
    float* out   = (float*)d_out;

    gat_proj<<<(N + 31) / 32, 256, 0, stream>>>(h, w, fc_w, hp, asrc, adst, N);

    int nvb   = (N + 15) / 16;           // 16 nodes per block (4 waves x 4)
    int chunk = (nvb + 7) / 8;
    gat_agg<<<8 * chunk, 256, 0, stream>>>(dst, (const uint4*)hp, asrc, adst,
                                           fc_b, bias, out, N);
}